// Round 17
// baseline (252.552 us; speedup 1.0000x reference)
//
#include <hip/hip_runtime.h>
#include <hip/hip_fp16.h>
#include <math.h>

#define NN 100000
#define EE 3200000
#define ET (EE + NN)

#define H1n 8
#define C1n 8
#define F1n 64
#define FINn 27
#define NEG 0.2f

// binning parameters (R14/R16 geometry)
#define NPB 128
#define NB 782
#define STRIDE 5120
#define TILE 4096
#define ABLK 256
#define EPT (TILE / ABLK)
#define WIN (STRIDE + NPB)
#define FBLK 512
#define RPT 10

typedef float floatx2 __attribute__((ext_vector_type(2)));

static __device__ __forceinline__ float lrelu(float v) {
    return v > 0.f ? v : NEG * v;
}

// ---------- phase A: bucket-sort edges into per-bucket record lists ----------
__global__ __launch_bounds__(ABLK) void k_binA(const int* __restrict__ ei,
                                               int* __restrict__ tail,
                                               int* __restrict__ recs) {
    __shared__ int hist[NB];
    __shared__ int lofs[NB];
    __shared__ int wofs[NB];
    __shared__ int sorted[TILE];
    __shared__ unsigned short sbkt[TILE];
    __shared__ int wls[ABLK / 64];

    int tid = threadIdx.x;
    long long e0 = (long long)blockIdx.x * TILE;
    int cnt = (int)min((long long)TILE, (long long)EE - e0);

    for (int i = tid; i < NB; i += ABLK) hist[i] = 0;
    __syncthreads();

    int ss[EPT], dd[EPT], rk[EPT];
    #pragma unroll
    for (int k = 0; k < EPT; ++k) {
        int idx = k * ABLK + tid;
        if (idx < cnt) {
            ss[k] = ei[e0 + idx];
            dd[k] = ei[EE + e0 + idx];
            rk[k] = atomicAdd(&hist[dd[k] >> 7], 1);
        }
    }
    __syncthreads();
    {
        const int CH = (NB + ABLK - 1) / ABLK;  // 4
        int beg = tid * CH, end = min(beg + CH, NB);
        int s = 0;
        for (int i = beg; i < end; ++i) s += hist[i];
        int lane = tid & 63, wv = tid >> 6;
        int inc = s;
        #pragma unroll
        for (int off = 1; off < 64; off <<= 1) {
            int t = __shfl_up(inc, off, 64);
            if (lane >= off) inc += t;
        }
        if (lane == 63) wls[wv] = inc;
        __syncthreads();
        int pre = 0;
        #pragma unroll
        for (int w = 0; w < ABLK / 64; ++w) pre += (w < wv) ? wls[w] : 0;
        int ex = pre + inc - s;
        for (int i = beg; i < end; ++i) {
            lofs[i] = ex;
            ex += hist[i];
        }
    }
    __syncthreads();
    #pragma unroll
    for (int k = 0; k < EPT; ++k) {
        int idx = k * ABLK + tid;
        if (idx < cnt) {
            int b = dd[k] >> 7;
            int r = lofs[b] + rk[k];
            sorted[r] = ss[k] | ((dd[k] & (NPB - 1)) << 17);
            sbkt[r] = (unsigned short)b;
        }
    }
    __syncthreads();
    for (int i = tid; i < NB; i += ABLK) {
        int c = hist[i];
        int g = (c > 0) ? atomicAdd(&tail[i], c) : 0;
        wofs[i] = g - lofs[i];
    }
    __syncthreads();
    for (int t = tid; t < cnt; t += ABLK) {
        int b = sbkt[t];
        recs[(size_t)b * STRIDE + wofs[b] + t] = sorted[t];
    }
}

// ---------- layer 1 node features, SPLIT half-tables ----------
// h1qA = channels 0..31 (fp8, 32B/row, 3.2MB); h1qB = channels 32..63.
// as1hA = heads 0..3 (4xf16, 8B/row, 0.8MB); as1hB = heads 4..7. ad1 f32 full.
__global__ __launch_bounds__(256) void k_h1(const float* __restrict__ x,
                                            const float* __restrict__ W1,
                                            const float* __restrict__ a_src1,
                                            const float* __restrict__ a_dst1,
                                            unsigned char* __restrict__ h1qA,
                                            unsigned char* __restrict__ h1qB,
                                            __half* __restrict__ as1hA,
                                            __half* __restrict__ as1hB,
                                            float* __restrict__ ad1) {
    int gt = blockIdx.x * blockDim.x + threadIdx.x;
    int n = gt >> 6;
    if (n >= NN) return;
    int lane = threadIdx.x & 63;
    const float* xr = x + (size_t)n * FINn;
    float s = 0.f;
    #pragma unroll
    for (int k = 0; k < FINn; ++k) s = fmaf(xr[k], W1[k * F1n + lane], s);
    float s2 = __shfl_down(s, 1, 64);
    if (!(lane & 1)) {
        int pk = __builtin_amdgcn_cvt_pk_fp8_f32(s, s2, 0, false);
        unsigned char* tb = (lane < 32) ? h1qA : h1qB;
        ((unsigned short*)(tb + (size_t)n * 32))[(lane & 31) >> 1] =
            (unsigned short)(pk & 0xFFFF);
    }
    float ps = s * a_src1[lane];
    float pd = s * a_dst1[lane];
    #pragma unroll
    for (int off = 1; off < 8; off <<= 1) {
        ps += __shfl_xor(ps, off, 64);
        pd += __shfl_xor(pd, off, 64);
    }
    if ((lane & 7) == 0) {
        int h = lane >> 3;
        __half* ta = (h < 4) ? as1hA : as1hB;
        ta[n * 4 + (h & 3)] = __float2half(ps);
        ad1[n * H1n + h] = pd;
    }
}

// ---------- per-bucket LDS counting sort -> gwin + nrange ----------
__global__ __launch_bounds__(FBLK) void k_sort(const int* __restrict__ recs,
                                               const int* __restrict__ tail,
                                               int* __restrict__ gwin,
                                               uint2* __restrict__ nrange) {
    __shared__ int hist[NPB];
    __shared__ int cur[NPB];
    __shared__ int rloc[NPB + 1];
    __shared__ int window[WIN];
    __shared__ int wtot[2];

    int b = blockIdx.x;
    int tid = threadIdx.x;
    int node0 = b * NPB;
    int nodes = min(NPB, NN - node0);
    int rcnt = tail[b];
    const int* rb = recs + (size_t)b * STRIDE;

    if (tid < NPB) hist[tid] = 0;
    __syncthreads();
    int rg[RPT];
    int nmine = 0;
    #pragma unroll
    for (int k = 0; k < RPT; ++k) {
        int i = tid + k * FBLK;
        if (i < rcnt) {
            rg[k] = rb[i];
            atomicAdd(&hist[rg[k] >> 17], 1);
            nmine = k + 1;
        }
    }
    __syncthreads();
    int v = 0, inc = 0;
    if (tid < NPB) {
        v = (tid < nodes) ? hist[tid] + 1 : 0;
        inc = v;
        #pragma unroll
        for (int off = 1; off < 64; off <<= 1) {
            int t = __shfl_up(inc, off, 64);
            if ((tid & 63) >= off) inc += t;
        }
        if ((tid & 63) == 63) wtot[tid >> 6] = inc;
    }
    __syncthreads();
    if (tid < NPB) {
        if (tid >= 64) inc += wtot[0];
        int ex = inc - v;
        if (tid < nodes) {
            rloc[tid] = ex;
            cur[tid] = ex + 1;
            window[ex] = node0 + tid;  // self-loop first
        }
    }
    if (tid == 0) rloc[nodes] = wtot[0] + wtot[1];
    __syncthreads();
    #pragma unroll
    for (int k = 0; k < RPT; ++k) {
        if (k < nmine) {
            int r = rg[k];
            int p = atomicAdd(&cur[r >> 17], 1);
            window[p] = r & 0x1FFFF;
        }
    }
    __syncthreads();
    int T = rloc[nodes];
    int gbase = b * WIN;
    for (int i = tid; i < T; i += FBLK)
        gwin[gbase + i] = window[i];
    if (tid < nodes) {
        uint2 r;
        r.x = (unsigned)(gbase + rloc[tid]);
        r.y = (unsigned)(gbase + rloc[tid + 1]);
        nrange[node0 + tid] = r;
    }
}

// ---------- layer-1 MP, ONE HEAD-HALF PER LAUNCH (L2-resident 4.0 MB) ----------
// PASS p: heads 4p..4p+3, channels 32p..32p+31, tables h1q{A,B}/as1h{A,B}.
// Score: lane=(e16=lane>>2, hh4=lane&3). Accum: lane=(q8=lane>>3, c4h=lane&7).
template <int PASS>
__global__ __launch_bounds__(FBLK) void k_mp2(const int* __restrict__ gwin,
                                              const uint2* __restrict__ nrange,
                                              const unsigned* __restrict__ h1h,
                                              const __half* __restrict__ as1h,
                                              const float* __restrict__ ad1,
                                              const float* __restrict__ b1,
                                              const float* __restrict__ W2,
                                              const float* __restrict__ a_src2,
                                              const float* __restrict__ a_dst2,
                                              float2* __restrict__ part,
                                              uint2* __restrict__ rec2) {
    int n = (int)(((unsigned)blockIdx.x * FBLK + threadIdx.x) >> 6);
    if (n >= NN) return;
    int lane = threadIdx.x & 63;
    int hh4 = lane & 3;
    int c4h = lane & 7;
    int bps = lane & 60;                         // (e16)<<2
    int bpq = (lane >> 3) << 2;                  // (q8)<<2
    int bpx = ((lane >> 3) << 4) + ((c4h >> 1) << 2);

    float adh = ad1[(n << 3) + (PASS << 2) + hh4];
    int ch0 = PASS * 32 + c4h * 4;
    float bch0 = b1[ch0 + 0], bch1 = b1[ch0 + 1];
    float bch2 = b1[ch0 + 2], bch3 = b1[ch0 + 3];
    float w2a0 = W2[(ch0 + 0) * 2], w2b0 = W2[(ch0 + 0) * 2 + 1];
    float w2a1 = W2[(ch0 + 1) * 2], w2b1 = W2[(ch0 + 1) * 2 + 1];
    float w2a2 = W2[(ch0 + 2) * 2], w2b2 = W2[(ch0 + 2) * 2 + 1];
    float w2a3 = W2[(ch0 + 3) * 2], w2b3 = W2[(ch0 + 3) * 2 + 1];

    uint2 rr = nrange[n];
    float a0 = 0.f, a1 = 0.f, a2 = 0.f, a3 = 0.f, den = 0.f;

    for (unsigned base = rr.x; base < rr.y; base += 64) {
        int cnt = (int)min(64u, rr.y - base);
        int sidx = (lane < cnt) ? __builtin_nontemporal_load(&gwin[base + lane]) : 0;
        for (int sb = 0; sb < cnt; sb += 16) {
            int sb4 = sb << 2;
            // score: 16 edges x 4 heads
            int s_sc = __builtin_amdgcn_ds_bpermute(sb4 + bps, sidx);
            float A = __half2float(as1h[((unsigned)s_sc << 2) + hh4]);
            float sc = A + adh;
            sc = fmaxf(sc, 0.2f * sc);
            float x = (sb + (lane >> 2) < cnt) ? __expf(sc) : 0.f;
            den += x;
            int xi = __float_as_int(x);
            // accumulate: 2 x (8 edges x 8 channel-quads)
            #pragma unroll
            for (int jj = 0; jj < 2; ++jj) {
                int s_a = __builtin_amdgcn_ds_bpermute(sb4 + (jj << 5) + bpq, sidx);
                int xr_ = __builtin_amdgcn_ds_bpermute((jj << 7) + bpx, xi);
                float xv = __int_as_float(xr_);
                unsigned dw = h1h[((unsigned)s_a << 3) + c4h];
                floatx2 lo = __builtin_amdgcn_cvt_pk_f32_fp8((int)dw, false);
                floatx2 hi = __builtin_amdgcn_cvt_pk_f32_fp8((int)dw, true);
                a0 = fmaf(xv, lo.x, a0);
                a1 = fmaf(xv, lo.y, a1);
                a2 = fmaf(xv, hi.x, a2);
                a3 = fmaf(xv, hi.y, a3);
            }
        }
    }

    // den: reduce over e16 slots (lane bits 2..5); lanes 0..3 hold heads 0..3
    den += __shfl_xor(den, 4, 64);
    den += __shfl_xor(den, 8, 64);
    den += __shfl_xor(den, 16, 64);
    den += __shfl_xor(den, 32, 64);
    den = __int_as_float(
        __builtin_amdgcn_ds_bpermute((c4h >> 1) << 2, __float_as_int(den)));
    // accums: reduce over q8 slots (lane bits 3..5)
    #pragma unroll
    for (int off = 8; off < 64; off <<= 1) {
        a0 += __shfl_xor(a0, off, 64);
        a1 += __shfl_xor(a1, off, 64);
        a2 += __shfl_xor(a2, off, 64);
        a3 += __shfl_xor(a3, off, 64);
    }
    float inv = 1.f / den;
    float v0 = a0 * inv + bch0;
    float v1 = a1 * inv + bch1;
    float v2 = a2 * inv + bch2;
    float v3 = a3 * inv + bch3;
    v0 = v0 > 0.f ? v0 : expm1f(v0);
    v1 = v1 > 0.f ? v1 : expm1f(v1);
    v2 = v2 > 0.f ? v2 : expm1f(v2);
    v3 = v3 > 0.f ? v3 : expm1f(v3);
    float p0 = v0 * w2a0 + v1 * w2a1 + v2 * w2a2 + v3 * w2a3;
    float p1 = v0 * w2b0 + v1 * w2b1 + v2 * w2b2 + v3 * w2b3;
    p0 += __shfl_xor(p0, 1, 64);
    p1 += __shfl_xor(p1, 1, 64);
    p0 += __shfl_xor(p0, 2, 64);
    p1 += __shfl_xor(p1, 2, 64);
    p0 += __shfl_xor(p0, 4, 64);
    p1 += __shfl_xor(p1, 4, 64);
    if (lane == 0) {
        if (PASS == 0) {
            part[n] = make_float2(p0, p1);
        } else {
            float2 pp = part[n];
            p0 += pp.x;
            p1 += pp.y;
            float as2 = p0 * a_src2[0] + p1 * a_src2[1];
            float ad2 = p0 * a_dst2[0] + p1 * a_dst2[1];
            __half2 lo2 = __floats2half2_rn(p0, p1);
            __half2 hi2 = __floats2half2_rn(as2, ad2);
            uint2 r;
            r.x = *(unsigned*)&lo2;
            r.y = *(unsigned*)&hi2;
            rec2[n] = r;
        }
    }
}

// ---------- layer-2: thread-per-node over exported CSR + log-softmax ----------
__global__ __launch_bounds__(256) void k_f2(const int* __restrict__ gwin,
                                            const uint2* __restrict__ nrange,
                                            const uint2* __restrict__ rec2,
                                            const float* __restrict__ b2,
                                            float* __restrict__ out) {
    int n = blockIdx.x * blockDim.x + threadIdx.x;
    if (n >= NN) return;
    __half2 mysd = *(const __half2*)&rec2[n].y;
    float adv = __half2float(__high2half(mysd));
    uint2 rr = nrange[n];
    float den = 0.f, a0 = 0.f, a1 = 0.f;
    for (unsigned i = rr.x; i < rr.y; ++i) {
        int s = gwin[i];
        uint2 rv = rec2[s];
        __half2 h01 = *(const __half2*)&rv.x;
        __half2 hsd = *(const __half2*)&rv.y;
        float e = lrelu(__half2float(__low2half(hsd)) + adv);
        float ex = __expf(e);
        den += ex;
        a0 = fmaf(ex, __half2float(__low2half(h01)), a0);
        a1 = fmaf(ex, __half2float(__high2half(h01)), a1);
    }
    float v0 = a0 / den + b2[0];
    float v1 = a1 / den + b2[1];
    float mx = fmaxf(v0, v1);
    float ls = mx + logf(__expf(v0 - mx) + __expf(v1 - mx));
    float2 o;
    o.x = v0 - ls;
    o.y = v1 - ls;
    ((float2*)out)[n] = o;
}

extern "C" void kernel_launch(void* const* d_in, const int* in_sizes, int n_in,
                              void* d_out, int out_size, void* d_ws, size_t ws_size,
                              hipStream_t stream) {
    const float* x      = (const float*)d_in[0];
    const int*   ei     = (const int*)d_in[1];
    const float* W1     = (const float*)d_in[2];
    const float* a_src1 = (const float*)d_in[3];
    const float* a_dst1 = (const float*)d_in[4];
    const float* b1     = (const float*)d_in[5];
    const float* W2     = (const float*)d_in[6];
    const float* a_src2 = (const float*)d_in[7];
    const float* a_dst2 = (const float*)d_in[8];
    const float* b2     = (const float*)d_in[9];
    float* out = (float*)d_out;

    char* wsb = (char*)d_ws;
    size_t o = 0;
    uint2* rec2 = (uint2*)wsb;                   o += (size_t)NN * 8;
    uint2* nrange = (uint2*)(wsb + o);           o += (size_t)NN * 8;
    float2* part = (float2*)(wsb + o);           o += (size_t)NN * 8;
    #define ALLOC(name, type, count) type* name = (type*)(wsb + o); o += (size_t)(count) * 4;
    ALLOC(ad1,    float, NN * H1n)
    ALLOC(recs,   int,   (size_t)NB * STRIDE)   // 16.0 MB
    ALLOC(gwin,   int,   (size_t)NB * WIN)      // 16.4 MB
    ALLOC(tail,   int,   NB)
    #undef ALLOC
    __half* as1hA = (__half*)(wsb + o);              o += (size_t)NN * 4 * 2;
    __half* as1hB = (__half*)(wsb + o);              o += (size_t)NN * 4 * 2;
    unsigned char* h1qA = (unsigned char*)(wsb + o); o += (size_t)NN * 32;
    unsigned char* h1qB = (unsigned char*)(wsb + o); o += (size_t)NN * 32;

    const int B = 256;
    #define GRID(n) ((unsigned)(((long long)(n) + B - 1) / B))

    // bucket records
    hipMemsetAsync(tail, 0, (size_t)NB * sizeof(int), stream);
    k_binA<<<(EE + TILE - 1) / TILE, ABLK, 0, stream>>>(ei, tail, recs);

    // layer-1 features (split half-tables)
    k_h1<<<GRID((size_t)NN * 64), B, 0, stream>>>(x, W1, a_src1, a_dst1,
                                                  h1qA, h1qB, as1hA, as1hB, ad1);

    // per-bucket counting sort -> gwin/nrange
    k_sort<<<NB, FBLK, 0, stream>>>(recs, tail, gwin, nrange);

    // layer-1 MP in two globally-synchronized passes (4.0 MB hot set each)
    unsigned mpg = (unsigned)(((size_t)NN * 64 + FBLK - 1) / FBLK);
    k_mp2<0><<<mpg, FBLK, 0, stream>>>(gwin, nrange, (const unsigned*)h1qA, as1hA,
                                       ad1, b1, W2, a_src2, a_dst2, part, rec2);
    k_mp2<1><<<mpg, FBLK, 0, stream>>>(gwin, nrange, (const unsigned*)h1qB, as1hB,
                                       ad1, b1, W2, a_src2, a_dst2, part, rec2);

    // layer-2 over exported CSR + log-softmax
    k_f2<<<GRID(NN), B, 0, stream>>>(gwin, nrange, rec2, b2, out);
    #undef GRID
}

// Round 18
// 210.018 us; speedup vs baseline: 1.2025x; 1.2025x over previous
//
#include <hip/hip_runtime.h>
#include <hip/hip_fp16.h>
#include <math.h>

#define NN 100000
#define EE 3200000
#define ET (EE + NN)

#define H1n 8
#define C1n 8
#define F1n 64
#define FINn 27
#define NEG 0.2f

// binning parameters (R14/R16 geometry)
#define NPB 128
#define NB 782
#define STRIDE 5120
#define TILE 4096
#define ABLK 512                // fused kernel: 8 waves
#define EPT (TILE / ABLK)       // 8 edges per thread
#define WIN (STRIDE + NPB)
#define FBLK 512
#define RPT 10

typedef float floatx2 __attribute__((ext_vector_type(2)));

static __device__ __forceinline__ float lrelu(float v) {
    return v > 0.f ? v : NEG * v;
}

// ---------- fused: phase-A bucket sort + layer-1 features ----------
// Block b: (1) bins its 4096-edge tile into per-bucket records;
//          (2) computes h1/as1/ad1 for its own 128 nodes (tail work that
//              overlaps other blocks' memory stalls on the same CU).
__global__ __launch_bounds__(ABLK) void k_binA_h1(const int* __restrict__ ei,
                                                  int* __restrict__ tail,
                                                  int* __restrict__ recs,
                                                  const float* __restrict__ x,
                                                  const float* __restrict__ W1,
                                                  const float* __restrict__ a_src1,
                                                  const float* __restrict__ a_dst1,
                                                  unsigned char* __restrict__ h1q,
                                                  __half* __restrict__ as1h,
                                                  float* __restrict__ ad1) {
    __shared__ int hist[NB];
    __shared__ int lofs[NB];
    __shared__ int wofs[NB];
    __shared__ int sorted[TILE];
    __shared__ unsigned short sbkt[TILE];
    __shared__ int wls[ABLK / 64];

    int tid = threadIdx.x;
    int b = blockIdx.x;
    long long e0 = (long long)b * TILE;
    int cnt = (int)min((long long)TILE, (long long)EE - e0);

    for (int i = tid; i < NB; i += ABLK) hist[i] = 0;
    __syncthreads();

    // ---- load 8 edges per thread via int4 (4 edges/load) + rank atomics ----
    int ss[EPT], dd[EPT], rk[EPT];
    #pragma unroll
    for (int j = 0; j < EPT / 4; ++j) {
        int idx4 = j * (ABLK * 4) + tid * 4;
        if (idx4 + 3 < cnt) {
            int4 sv = *(const int4*)&ei[e0 + idx4];
            int4 dv = *(const int4*)&ei[EE + e0 + idx4];
            ss[j * 4 + 0] = sv.x; ss[j * 4 + 1] = sv.y;
            ss[j * 4 + 2] = sv.z; ss[j * 4 + 3] = sv.w;
            dd[j * 4 + 0] = dv.x; dd[j * 4 + 1] = dv.y;
            dd[j * 4 + 2] = dv.z; dd[j * 4 + 3] = dv.w;
            #pragma unroll
            for (int c = 0; c < 4; ++c)
                rk[j * 4 + c] = atomicAdd(&hist[dd[j * 4 + c] >> 7], 1);
        } else {
            #pragma unroll
            for (int c = 0; c < 4; ++c) {
                int idx = idx4 + c;
                if (idx < cnt) {
                    ss[j * 4 + c] = ei[e0 + idx];
                    dd[j * 4 + c] = ei[EE + e0 + idx];
                    rk[j * 4 + c] = atomicAdd(&hist[dd[j * 4 + c] >> 7], 1);
                }
            }
        }
    }
    __syncthreads();
    // ---- exclusive scan of hist -> lofs (shfl wave-scan + fixup) ----
    {
        const int CH = (NB + ABLK - 1) / ABLK;  // 2
        int beg = tid * CH, end = min(beg + CH, NB);
        int s = 0;
        for (int i = beg; i < end; ++i) s += hist[i];
        int lane = tid & 63, wv = tid >> 6;
        int inc = s;
        #pragma unroll
        for (int off = 1; off < 64; off <<= 1) {
            int t = __shfl_up(inc, off, 64);
            if (lane >= off) inc += t;
        }
        if (lane == 63) wls[wv] = inc;
        __syncthreads();
        int pre = 0;
        #pragma unroll
        for (int w = 0; w < ABLK / 64; ++w) pre += (w < wv) ? wls[w] : 0;
        int ex = pre + inc - s;
        for (int i = beg; i < end; ++i) {
            lofs[i] = ex;
            ex += hist[i];
        }
    }
    __syncthreads();
    // ---- stage bucket-sorted records in LDS ----
    #pragma unroll
    for (int j = 0; j < EPT / 4; ++j) {
        #pragma unroll
        for (int c = 0; c < 4; ++c) {
            int k = j * 4 + c;
            int idx = j * (ABLK * 4) + tid * 4 + c;
            if (idx < cnt) {
                int bb = dd[k] >> 7;
                int r = lofs[bb] + rk[k];
                sorted[r] = ss[k] | ((dd[k] & (NPB - 1)) << 17);
                sbkt[r] = (unsigned short)bb;
            }
        }
    }
    __syncthreads();
    // ---- reserve global space; wofs = gpos - lofs ----
    for (int i = tid; i < NB; i += ABLK) {
        int c = hist[i];
        int g = (c > 0) ? atomicAdd(&tail[i], c) : 0;
        wofs[i] = g - lofs[i];
    }
    __syncthreads();
    for (int t = tid; t < cnt; t += ABLK) {
        int bb = sbkt[t];
        recs[(size_t)bb * STRIDE + wofs[bb] + t] = sorted[t];
    }

    // ---- layer-1 features for this block's 128 nodes (no LDS, no syncs) ----
    {
        int lane = tid & 63;
        int wv = tid >> 6;          // 0..7, 16 nodes each
        float asl = a_src1[lane];
        float adl = a_dst1[lane];
        for (int m = 0; m < NPB / 8; ++m) {
            int n = b * NPB + wv * (NPB / 8) + m;
            if (n >= NN) break;
            const float* xr = x + (size_t)n * FINn;
            float s = 0.f;
            #pragma unroll
            for (int k = 0; k < FINn; ++k) s = fmaf(xr[k], W1[k * F1n + lane], s);
            float s2 = __shfl_down(s, 1, 64);
            if (!(lane & 1)) {
                int pk = __builtin_amdgcn_cvt_pk_fp8_f32(s, s2, 0, false);
                ((unsigned short*)(h1q + (size_t)n * F1n))[lane >> 1] =
                    (unsigned short)(pk & 0xFFFF);
            }
            float ps = s * asl;
            float pd = s * adl;
            #pragma unroll
            for (int off = 1; off < 8; off <<= 1) {
                ps += __shfl_xor(ps, off, 64);
                pd += __shfl_xor(pd, off, 64);
            }
            if ((lane & 7) == 0) {
                int h = lane >> 3;
                as1h[n * H1n + h] = __float2half(ps);
                ad1[n * H1n + h] = pd;
            }
        }
    }
}

// ---------- per-bucket LDS counting sort -> gwin + nrange ----------
__global__ __launch_bounds__(FBLK) void k_sort(const int* __restrict__ recs,
                                               const int* __restrict__ tail,
                                               int* __restrict__ gwin,
                                               uint2* __restrict__ nrange) {
    __shared__ int hist[NPB];
    __shared__ int cur[NPB];
    __shared__ int rloc[NPB + 1];
    __shared__ int window[WIN];
    __shared__ int wtot[2];

    int b = blockIdx.x;
    int tid = threadIdx.x;
    int node0 = b * NPB;
    int nodes = min(NPB, NN - node0);
    int rcnt = tail[b];
    const int* rb = recs + (size_t)b * STRIDE;

    if (tid < NPB) hist[tid] = 0;
    __syncthreads();
    int rg[RPT];
    int nmine = 0;
    #pragma unroll
    for (int k = 0; k < RPT; ++k) {
        int i = tid + k * FBLK;
        if (i < rcnt) {
            rg[k] = rb[i];
            atomicAdd(&hist[rg[k] >> 17], 1);
            nmine = k + 1;
        }
    }
    __syncthreads();
    int v = 0, inc = 0;
    if (tid < NPB) {
        v = (tid < nodes) ? hist[tid] + 1 : 0;
        inc = v;
        #pragma unroll
        for (int off = 1; off < 64; off <<= 1) {
            int t = __shfl_up(inc, off, 64);
            if ((tid & 63) >= off) inc += t;
        }
        if ((tid & 63) == 63) wtot[tid >> 6] = inc;
    }
    __syncthreads();
    if (tid < NPB) {
        if (tid >= 64) inc += wtot[0];
        int ex = inc - v;
        if (tid < nodes) {
            rloc[tid] = ex;
            cur[tid] = ex + 1;
            window[ex] = node0 + tid;  // self-loop first
        }
    }
    if (tid == 0) rloc[nodes] = wtot[0] + wtot[1];
    __syncthreads();
    #pragma unroll
    for (int k = 0; k < RPT; ++k) {
        if (k < nmine) {
            int r = rg[k];
            int p = atomicAdd(&cur[r >> 17], 1);
            window[p] = r & 0x1FFFF;
        }
    }
    __syncthreads();
    int T = rloc[nodes];
    int gbase = b * WIN;
    for (int i = tid; i < T; i += FBLK)
        gwin[gbase + i] = window[i];
    if (tid < nodes) {
        uint2 r;
        r.x = (unsigned)(gbase + rloc[tid]);
        r.y = (unsigned)(gbase + rloc[tid + 1]);
        nrange[node0 + tid] = r;
    }
}

// ---------- layer-1 MP + ELU + L2 projection: one wave per node, no LDS ----------
__global__ __launch_bounds__(FBLK) void k_mp(const int* __restrict__ gwin,
                                             const uint2* __restrict__ nrange,
                                             const unsigned* __restrict__ h1q,
                                             const __half* __restrict__ as1h,
                                             const float* __restrict__ ad1,
                                             const float* __restrict__ b1,
                                             const float* __restrict__ W2,
                                             const float* __restrict__ a_src2,
                                             const float* __restrict__ a_dst2,
                                             uint2* __restrict__ rec2) {
    int n = (int)(((unsigned)blockIdx.x * FBLK + threadIdx.x) >> 6);
    if (n >= NN) return;
    int lane = threadIdx.x & 63;
    int e8 = lane >> 3;
    int hh = lane & 7;
    int q = lane >> 4;
    int c4 = lane & 15;
    int bpe = e8 << 2;
    int bpq = q << 2;
    int bpx = ((q << 3) + (c4 >> 1)) << 2;

    float adh = ad1[(n << 3) + hh];
    uint2 rr = nrange[n];
    float a0 = 0.f, a1 = 0.f, a2 = 0.f, a3 = 0.f, den = 0.f;

    for (unsigned base = rr.x; base < rr.y; base += 64) {
        int cnt = (int)min(64u, rr.y - base);
        int sidx = (lane < cnt) ? gwin[base + lane] : 0;
        for (int sb = 0; sb < cnt; sb += 8) {
            int sb4 = sb << 2;
            int s_sc = __builtin_amdgcn_ds_bpermute(sb4 + bpe, sidx);
            float A = __half2float(as1h[((unsigned)s_sc << 3) + hh]);
            float sc = A + adh;
            sc = fmaxf(sc, 0.2f * sc);
            float x = (sb + e8 < cnt) ? __expf(sc) : 0.f;
            den += x;
            int xi = __float_as_int(x);
            #pragma unroll
            for (int jj = 0; jj < 2; ++jj) {
                int s_a = __builtin_amdgcn_ds_bpermute(sb4 + (jj << 4) + bpq, sidx);
                int xr_ = __builtin_amdgcn_ds_bpermute((jj << 7) + bpx, xi);
                float xv = __int_as_float(xr_);
                unsigned dw = h1q[((unsigned)s_a << 4) + c4];
                floatx2 lo = __builtin_amdgcn_cvt_pk_f32_fp8((int)dw, false);
                floatx2 hi = __builtin_amdgcn_cvt_pk_f32_fp8((int)dw, true);
                a0 = fmaf(xv, lo.x, a0);
                a1 = fmaf(xv, lo.y, a1);
                a2 = fmaf(xv, hi.x, a2);
                a3 = fmaf(xv, hi.y, a3);
            }
        }
    }

    den += __shfl_xor(den, 8, 64);
    den += __shfl_xor(den, 16, 64);
    den += __shfl_xor(den, 32, 64);
    den = __int_as_float(
        __builtin_amdgcn_ds_bpermute((c4 >> 1) << 2, __float_as_int(den)));
    #pragma unroll
    for (int off = 16; off < 64; off <<= 1) {
        a0 += __shfl_xor(a0, off, 64);
        a1 += __shfl_xor(a1, off, 64);
        a2 += __shfl_xor(a2, off, 64);
        a3 += __shfl_xor(a3, off, 64);
    }
    float inv = 1.f / den;
    float v0 = a0 * inv + b1[c4 * 4 + 0];
    float v1 = a1 * inv + b1[c4 * 4 + 1];
    float v2 = a2 * inv + b1[c4 * 4 + 2];
    float v3 = a3 * inv + b1[c4 * 4 + 3];
    v0 = v0 > 0.f ? v0 : expm1f(v0);
    v1 = v1 > 0.f ? v1 : expm1f(v1);
    v2 = v2 > 0.f ? v2 : expm1f(v2);
    v3 = v3 > 0.f ? v3 : expm1f(v3);
    float p0 = v0 * W2[(c4 * 4 + 0) * 2 + 0] + v1 * W2[(c4 * 4 + 1) * 2 + 0] +
               v2 * W2[(c4 * 4 + 2) * 2 + 0] + v3 * W2[(c4 * 4 + 3) * 2 + 0];
    float p1 = v0 * W2[(c4 * 4 + 0) * 2 + 1] + v1 * W2[(c4 * 4 + 1) * 2 + 1] +
               v2 * W2[(c4 * 4 + 2) * 2 + 1] + v3 * W2[(c4 * 4 + 3) * 2 + 1];
    #pragma unroll
    for (int off = 1; off < 16; off <<= 1) {
        p0 += __shfl_xor(p0, off, 64);
        p1 += __shfl_xor(p1, off, 64);
    }
    if (lane == 0) {
        float as2 = p0 * a_src2[0] + p1 * a_src2[1];
        float ad2 = p0 * a_dst2[0] + p1 * a_dst2[1];
        __half2 lo2 = __floats2half2_rn(p0, p1);
        __half2 hi2 = __floats2half2_rn(as2, ad2);
        uint2 r;
        r.x = *(unsigned*)&lo2;
        r.y = *(unsigned*)&hi2;
        rec2[n] = r;
    }
}

// ---------- layer-2: thread-per-node over exported CSR + log-softmax ----------
__global__ __launch_bounds__(256) void k_f2(const int* __restrict__ gwin,
                                            const uint2* __restrict__ nrange,
                                            const uint2* __restrict__ rec2,
                                            const float* __restrict__ b2,
                                            float* __restrict__ out) {
    int n = blockIdx.x * blockDim.x + threadIdx.x;
    if (n >= NN) return;
    __half2 mysd = *(const __half2*)&rec2[n].y;
    float adv = __half2float(__high2half(mysd));
    uint2 rr = nrange[n];
    float den = 0.f, a0 = 0.f, a1 = 0.f;
    for (unsigned i = rr.x; i < rr.y; ++i) {
        int s = gwin[i];
        uint2 rv = rec2[s];
        __half2 h01 = *(const __half2*)&rv.x;
        __half2 hsd = *(const __half2*)&rv.y;
        float e = lrelu(__half2float(__low2half(hsd)) + adv);
        float ex = __expf(e);
        den += ex;
        a0 = fmaf(ex, __half2float(__low2half(h01)), a0);
        a1 = fmaf(ex, __half2float(__high2half(h01)), a1);
    }
    float v0 = a0 / den + b2[0];
    float v1 = a1 / den + b2[1];
    float mx = fmaxf(v0, v1);
    float ls = mx + logf(__expf(v0 - mx) + __expf(v1 - mx));
    float2 o;
    o.x = v0 - ls;
    o.y = v1 - ls;
    ((float2*)out)[n] = o;
}

extern "C" void kernel_launch(void* const* d_in, const int* in_sizes, int n_in,
                              void* d_out, int out_size, void* d_ws, size_t ws_size,
                              hipStream_t stream) {
    const float* x      = (const float*)d_in[0];
    const int*   ei     = (const int*)d_in[1];
    const float* W1     = (const float*)d_in[2];
    const float* a_src1 = (const float*)d_in[3];
    const float* a_dst1 = (const float*)d_in[4];
    const float* b1     = (const float*)d_in[5];
    const float* W2     = (const float*)d_in[6];
    const float* a_src2 = (const float*)d_in[7];
    const float* a_dst2 = (const float*)d_in[8];
    const float* b2     = (const float*)d_in[9];
    float* out = (float*)d_out;

    char* wsb = (char*)d_ws;
    size_t o = 0;
    uint2* rec2 = (uint2*)wsb;                   o += (size_t)NN * 8;
    uint2* nrange = (uint2*)(wsb + o);           o += (size_t)NN * 8;
    #define ALLOC(name, type, count) type* name = (type*)(wsb + o); o += (size_t)(count) * 4;
    ALLOC(ad1,    float, NN * H1n)
    ALLOC(recs,   int,   (size_t)NB * STRIDE)   // 16.0 MB
    ALLOC(gwin,   int,   (size_t)NB * WIN)      // 16.4 MB
    ALLOC(tail,   int,   NB)
    #undef ALLOC
    __half* as1h = (__half*)(wsb + o);               o += (size_t)NN * H1n * 2;
    unsigned char* h1q = (unsigned char*)(wsb + o);  o += (size_t)NN * F1n;

    const int B = 256;
    #define GRID(n) ((unsigned)(((long long)(n) + B - 1) / B))

    // bucket records + layer-1 features (fused: h1 is per-block tail work)
    hipMemsetAsync(tail, 0, (size_t)NB * sizeof(int), stream);
    k_binA_h1<<<(EE + TILE - 1) / TILE, ABLK, 0, stream>>>(
        ei, tail, recs, x, W1, a_src1, a_dst1, h1q, as1h, ad1);

    // per-bucket counting sort -> gwin/nrange
    k_sort<<<NB, FBLK, 0, stream>>>(recs, tail, gwin, nrange);

    // layer-1 MP + ELU + layer-2 projection (one wave per node, no LDS)
    k_mp<<<(unsigned)(((size_t)NN * 64 + FBLK - 1) / FBLK), FBLK, 0, stream>>>(
        gwin, nrange, (const unsigned*)h1q, as1h, ad1, b1, W2, a_src2, a_dst2, rec2);

    // layer-2 over exported CSR + log-softmax
    k_f2<<<GRID(NN), B, 0, stream>>>(gwin, nrange, rec2, b2, out);
    #undef GRID
}